// Round 16
// baseline (13.166 us; speedup 1.0000x reference)
//
#include <hip/hip_runtime.h>
#include <stdint.h>

// FSUConv2d single-cycle bipolar forward == binary XNOR-conv with threshold:
//   per tap popc(x&w) + popc(~x&~w) = 64 - popc(x^w); zero-padded tile makes
//   pad taps follow the same formula. pc = 576 - S + b_bit, S = sum popc(x^w).
//   out = (pc >= 577) = (S == 0 && b_bit) = (all 9 tap words EQUAL && b_bit).
//
// Single dispatch, 224 blocks x 1024 threads, pipelined (R13) + lazy halo
// (R14) + 32-channel hot slice (R15) + WIDE CONV PHASE (new): 896 conv
// threads (1 cout x 2 rows x 4 cols each per chunk) instead of 448 x 2couts
// -> 2x store-issue concurrency in the write phases, half the idle waves.
//   A: pack xt_lo rows 1..3 + wcen(ch0..31) + flags.
//   B: tids 0..895 conv chunk 0 (u32 center reject -> zero stores)
//      tids 896..951 pack xt_lo row 4 concurrently.
//   C: conv chunk 1.
//   D: (cold, P~2^-32/word) xt_hi + halo + pads + full weights -> exact eval.

#define NB   16
#define CIN  64
#define HH   56
#define WWD  56
#define COUT 64
#define HW   (HH * WWD)             // 3136
#define RPB  4
#define BANDS (HH / RPB)            // 14
#define NBLOCKS (NB * BANDS)        // 224
#define XT_STRIDE 60                // uint32 row stride; 240B rows, 16B-aligned
#define NTHREADS 1024

__global__ __launch_bounds__(NTHREADS) void fused_conv(const float* __restrict__ x,
                                                       const float* __restrict__ w,
                                                       const float* __restrict__ bias,
                                                       float* __restrict__ out) {
    __shared__ uint32_t xt_lo[6 * XT_STRIDE];   // channels 0..31 (hot)
    __shared__ uint32_t xt_hi[6 * XT_STRIDE];   // channels 32..63 (lazy)
    __shared__ uint64_t wsh[COUT * 9];          // full weight words (lazy)
    __shared__ uint32_t wcen[COUT];             // center-tap ch0..31 (hot)
    __shared__ int bflag[COUT];
    __shared__ int needflag[COUT];
    __shared__ int anyneed;

    int n    = blockIdx.x / BANDS;
    int band = blockIdx.x % BANDS;
    int h0   = band * RPB;
    int tid  = threadIdx.x;
    int wid  = tid >> 6;
    int lane = tid & 63;

    // pack one (xt row, 8ch-group cg in [0,4), 4px quad) task; ch = chbase+8cg+i
    auto pack_task = [&](uint32_t* xtbuf, int chbase, int row, int rem) {
        int cg  = rem / 14;
        int pg  = rem - cg * 14;
        int gh  = h0 - 1 + row;
        int pc0 = pg * 4;
        uint32_t b0 = 0, b1 = 0, b2 = 0, b3 = 0;
        if (gh >= 0 && gh < HH) {
            const float* xp = x + (size_t)n * CIN * HW + (size_t)(chbase + cg * 8) * HW
                                + (size_t)gh * WWD + pc0;
#pragma unroll
            for (int i = 0; i < 8; ++i) {
                float4 v = *(const float4*)(xp + (size_t)i * HW);
                b0 |= (uint32_t)(v.x != 0.0f) << i;
                b1 |= (uint32_t)(v.y != 0.0f) << i;
                b2 |= (uint32_t)(v.z != 0.0f) << i;
                b3 |= (uint32_t)(v.w != 0.0f) << i;
            }
        }
        uint8_t* xb = (uint8_t*)xtbuf;
        int base = (row * XT_STRIDE + 1 + pc0) * 4 + cg;
        xb[base]      = (uint8_t)b0;
        xb[base + 4]  = (uint8_t)b1;
        xb[base + 8]  = (uint8_t)b2;
        xb[base + 12] = (uint8_t)b3;
    };

    // ---- phase A: pack xt_lo rows 1..3; wcen (2 couts per wave-load); flags
    if (tid < 168) pack_task(xt_lo, 0, 1 + tid / 56, tid % 56);
#pragma unroll
    for (int j = 0; j < 2; ++j) {
        int co = wid * 4 + 2 * j + (lane >> 5);
        int c  = lane & 31;
        float f = w[(size_t)co * (CIN * 9) + (size_t)c * 9 + 4];
        uint64_t qb = __ballot(f > 0.0f);
        if (lane == 0) {
            wcen[wid * 4 + 2 * j]     = (uint32_t)qb;
            wcen[wid * 4 + 2 * j + 1] = (uint32_t)(qb >> 32);
        }
    }
    if (tid < COUT) {
        bflag[tid]    = bias[tid] > 0.0f;
        needflag[tid] = 0;
    }
    if (tid == 0) anyneed = 0;
    __syncthreads();

    bool isconv = tid < 896;
    int c0 = 0, co = 0, bb = 0;
    uint32_t wc = 0;
    if (isconv) {
        co = tid / 14;                    // one cout per thread
        int q = tid - co * 14;
        c0 = q * 4;
        wc = wcen[co];
        bb = bflag[co];
    }

    // hot: 32-bit center-tap reject for out rows h0+2*chunk, h0+2*chunk+1
    auto chunk_hot = [&](int chunk) -> bool {
        uint32_t rc[2][6];
#pragma unroll
        for (int r = 0; r < 2; ++r) {
            const uint32_t* base = &xt_lo[(2 * chunk + 1 + r) * XT_STRIDE + c0];
            uint4 a = *(const uint4*)base;       // 240B rows, c0=4q -> 16B aligned
            uint2 b = *(const uint2*)(base + 4);
            rc[r][0] = a.x; rc[r][1] = a.y; rc[r][2] = a.z;
            rc[r][3] = a.w; rc[r][4] = b.x; rc[r][5] = b.y;
        }
        int hit = 0;
#pragma unroll
        for (int r = 0; r < 2; ++r)
#pragma unroll
            for (int o = 0; o < 4; ++o) hit |= (rc[r][o + 1] == wc);
        bool need = (hit & bb) != 0;
        float* ob = out + ((size_t)n * COUT + co) * HW
                        + (size_t)(h0 + 2 * chunk) * WWD + c0;
        if (need) {                       // benign races: only ever write 1
            needflag[co] = 1;
            anyneed      = 1;
        } else {
            float4 z = make_float4(0.0f, 0.0f, 0.0f, 0.0f);
            *(float4*)ob         = z;
            *(float4*)(ob + WWD) = z;
        }
        return need;
    };

    // ---- phase B: conv chunk 0 (stores) || pack xt_lo row 4 (reads)
    bool need_b = false, need_c = false;
    if (isconv) {
        need_b = chunk_hot(0);
    } else {
        int t2 = tid - 896;
        if (t2 < 56) pack_task(xt_lo, 0, 4, t2);
    }
    __syncthreads();

    // ---- phase C: conv chunk 1
    if (isconv) need_c = chunk_hot(1);
    __syncthreads();

    // ---- phase D1 (cold): xt_hi rows 0..5, xt_lo halo rows 0/5, pads, weights
    if (anyneed) {
        if (tid < 336) {
            pack_task(xt_hi, 32, tid / 56, tid % 56);
        } else if (tid < 448) {
            int t2 = tid - 336;
            pack_task(xt_lo, 0, (t2 < 56) ? 0 : 5, t2 % 56);
        } else if (tid < 472) {
            int i  = tid - 448;               // 24 pad-column words
            uint32_t* buf = (i < 12) ? xt_lo : xt_hi;
            int ii = i % 12;
            buf[(ii >> 1) * XT_STRIDE + ((ii & 1) ? 57 : 0)] = 0u;
        }
#pragma unroll
        for (int i = 0; i < 4; ++i) {
            int cw = wid * 4 + i;
            if (needflag[cw]) {               // wave-uniform (same LDS word)
                const float* ws = w + (size_t)cw * (CIN * 9) + (size_t)lane * 9;
#pragma unroll
                for (int k = 0; k < 9; ++k) {
                    uint64_t qb = __ballot(ws[k] > 0.0f);
                    if (lane == 0) wsh[cw * 9 + k] = qb;
                }
            }
        }
    }
    __syncthreads();

    // ---- phase D2 (cold): exact 64-bit 9-tap equality eval for hit chunks
    if (need_b | need_c) {
        uint64_t wp[9];
#pragma unroll
        for (int k = 0; k < 9; ++k) wp[k] = wsh[co * 9 + k];
#pragma unroll
        for (int chunk = 0; chunk < 2; ++chunk) {
            bool nd = chunk ? need_c : need_b;
            if (!nd) continue;
            uint64_t rA[4][6];
#pragma unroll
            for (int r = 0; r < 4; ++r)
#pragma unroll
                for (int c = 0; c < 6; ++c) {
                    int idx = (2 * chunk + r) * XT_STRIDE + c0 + c;
                    rA[r][c] = (uint64_t)xt_lo[idx] | ((uint64_t)xt_hi[idx] << 32);
                }
            float* ob = out + ((size_t)n * COUT + co) * HW
                            + (size_t)(h0 + 2 * chunk) * WWD + c0;
#pragma unroll
            for (int r = 0; r < 2; ++r) {
                float v[4];
#pragma unroll
                for (int o = 0; o < 4; ++o) {
                    int e = bb;
#pragma unroll
                    for (int kh = 0; kh < 3; ++kh)
#pragma unroll
                        for (int kw = 0; kw < 3; ++kw)
                            e &= (rA[r + kh][o + kw] == wp[kh * 3 + kw]);
                    v[o] = e ? 1.0f : 0.0f;
                }
                *(float4*)(ob + (size_t)r * WWD) =
                    make_float4(v[0], v[1], v[2], v[3]);
            }
        }
    }
}

extern "C" void kernel_launch(void* const* d_in, const int* in_sizes, int n_in,
                              void* d_out, int out_size, void* d_ws, size_t ws_size,
                              hipStream_t stream) {
    const float* x    = (const float*)d_in[0];
    const float* wgt  = (const float*)d_in[1];
    const float* bias = (const float*)d_in[2];
    float* out = (float*)d_out;

    fused_conv<<<NBLOCKS, NTHREADS, 0, stream>>>(x, wgt, bias, out);
}

// Round 17
// 10.912 us; speedup vs baseline: 1.2066x; 1.2066x over previous
//
#include <hip/hip_runtime.h>
#include <stdint.h>

// FSUConv2d single-cycle bipolar forward == binary XNOR-conv with threshold:
//   per tap popc(x&w) + popc(~x&~w) = 64 - popc(x^w); zero-padded tile makes
//   pad taps follow the same formula. pc = 576 - S + b_bit, S = sum popc(x^w).
//   out = (pc >= 577) = (S == 0 && b_bit) = (all 9 tap words EQUAL && b_bit).
//
// R17 = exact revert to R15 (best measured: 11.03us). R16's wide-conv phase
// regressed (-2.1us): doubling conv threads doubled hot-phase LDS reads;
// store-issue width was never binding. Structure:
// Single dispatch, 224 blocks x 1024 threads, pipelined (R13) + lazy halo
// (R14) + 32-channel hot slice (R15): the center-tap rejector tests only
// channels 0..31 (P(pass) = 2^-32 per word on random bitstreams); hot path
// packs only xt_lo (6.4 MB machine-wide x reads) and 18 weight lines/cout.
// Channels 32..63 (xt_hi), halo rows, pad cols, and full 9-tap weight words
// are packed lazily behind the anyneed gate; the exact 64-bit 9-tap eval
// guarantees correctness for arbitrary (adversarial) inputs.
//   A: pack xt_lo rows 1..3 + wcen(ch0..31, 2 couts/wave-load) + flags.
//   B: tids 0..447 conv chunk 0 (u32 center reject -> zero stores)
//      tids 448..503 pack xt_lo row 4 concurrently.
//   C: conv chunk 1.
//   D: (cold) xt_hi all rows + xt_lo halo + pads + full weights -> exact.

#define NB   16
#define CIN  64
#define HH   56
#define WWD  56
#define COUT 64
#define HW   (HH * WWD)             // 3136
#define RPB  4
#define BANDS (HH / RPB)            // 14
#define NBLOCKS (NB * BANDS)        // 224
#define XT_STRIDE 60                // uint32 row stride; 240B = 16B-aligned rows
#define NTHREADS 1024

__global__ __launch_bounds__(NTHREADS) void fused_conv(const float* __restrict__ x,
                                                       const float* __restrict__ w,
                                                       const float* __restrict__ bias,
                                                       float* __restrict__ out) {
    __shared__ uint32_t xt_lo[6 * XT_STRIDE];   // channels 0..31 (hot)
    __shared__ uint32_t xt_hi[6 * XT_STRIDE];   // channels 32..63 (lazy)
    __shared__ uint64_t wsh[COUT * 9];          // full weight words (lazy)
    __shared__ uint32_t wcen[COUT];             // center-tap ch0..31 (hot)
    __shared__ int bflag[COUT];
    __shared__ int needflag[COUT];
    __shared__ int anyneed;

    int n    = blockIdx.x / BANDS;
    int band = blockIdx.x % BANDS;
    int h0   = band * RPB;
    int tid  = threadIdx.x;
    int wid  = tid >> 6;
    int lane = tid & 63;

    // pack one (xt row, 8ch-group cg in [0,4), 4px quad) task; ch = chbase+8cg+i
    auto pack_task = [&](uint32_t* xtbuf, int chbase, int row, int rem) {
        int cg  = rem / 14;
        int pg  = rem - cg * 14;
        int gh  = h0 - 1 + row;
        int pc0 = pg * 4;
        uint32_t b0 = 0, b1 = 0, b2 = 0, b3 = 0;
        if (gh >= 0 && gh < HH) {
            const float* xp = x + (size_t)n * CIN * HW + (size_t)(chbase + cg * 8) * HW
                                + (size_t)gh * WWD + pc0;
#pragma unroll
            for (int i = 0; i < 8; ++i) {
                float4 v = *(const float4*)(xp + (size_t)i * HW);
                b0 |= (uint32_t)(v.x != 0.0f) << i;
                b1 |= (uint32_t)(v.y != 0.0f) << i;
                b2 |= (uint32_t)(v.z != 0.0f) << i;
                b3 |= (uint32_t)(v.w != 0.0f) << i;
            }
        }
        uint8_t* xb = (uint8_t*)xtbuf;
        int base = (row * XT_STRIDE + 1 + pc0) * 4 + cg;
        xb[base]      = (uint8_t)b0;
        xb[base + 4]  = (uint8_t)b1;
        xb[base + 8]  = (uint8_t)b2;
        xb[base + 12] = (uint8_t)b3;
    };

    // ---- phase A: pack xt_lo rows 1..3; wcen (2 couts per wave-load); flags
    if (tid < 168) pack_task(xt_lo, 0, 1 + tid / 56, tid % 56);
#pragma unroll
    for (int j = 0; j < 2; ++j) {
        int co = wid * 4 + 2 * j + (lane >> 5);
        int c  = lane & 31;
        float f = w[(size_t)co * (CIN * 9) + (size_t)c * 9 + 4];
        uint64_t qb = __ballot(f > 0.0f);
        if (lane == 0) {
            wcen[wid * 4 + 2 * j]     = (uint32_t)qb;
            wcen[wid * 4 + 2 * j + 1] = (uint32_t)(qb >> 32);
        }
    }
    if (tid < COUT) {
        bflag[tid]    = bias[tid] > 0.0f;
        needflag[tid] = 0;
    }
    if (tid == 0) anyneed = 0;
    __syncthreads();

    bool isconv = tid < 448;
    int c0 = 0, co0 = 0, bb0 = 0, bb1 = 0;
    uint32_t wc0 = 0, wc1 = 0;
    if (isconv) {
        int q  = tid % 14;
        int cp = tid / 14;
        c0  = q * 4;
        co0 = cp * 2;
        wc0 = wcen[co0];
        wc1 = wcen[co0 + 1];
        bb0 = bflag[co0];
        bb1 = bflag[co0 + 1];
    }

    // hot: 32-bit center-tap reject for out rows h0+2*chunk, h0+2*chunk+1
    auto chunk_hot = [&](int chunk) -> bool {
        uint32_t rc[2][6];
#pragma unroll
        for (int r = 0; r < 2; ++r) {
            const uint32_t* base = &xt_lo[(2 * chunk + 1 + r) * XT_STRIDE + c0];
            uint4 a = *(const uint4*)base;       // 16B-aligned: stride 240, c0=4q
            uint2 b = *(const uint2*)(base + 4);
            rc[r][0] = a.x; rc[r][1] = a.y; rc[r][2] = a.z;
            rc[r][3] = a.w; rc[r][4] = b.x; rc[r][5] = b.y;
        }
        int hit0 = 0, hit1 = 0;
#pragma unroll
        for (int r = 0; r < 2; ++r)
#pragma unroll
            for (int o = 0; o < 4; ++o) {
                uint32_t cw = rc[r][o + 1];
                hit0 |= (cw == wc0);
                hit1 |= (cw == wc1);
            }
        bool need = ((hit0 & bb0) | (hit1 & bb1)) != 0;
        float* ob0 = out + ((size_t)n * COUT + co0) * HW
                         + (size_t)(h0 + 2 * chunk) * WWD + c0;
        if (need) {                       // benign races: only ever write 1
            needflag[co0]     = 1;
            needflag[co0 + 1] = 1;
            anyneed           = 1;
        } else {
            float4 z = make_float4(0.0f, 0.0f, 0.0f, 0.0f);
            *(float4*)ob0              = z;
            *(float4*)(ob0 + WWD)      = z;
            *(float4*)(ob0 + HW)       = z;
            *(float4*)(ob0 + HW + WWD) = z;
        }
        return need;
    };

    // ---- phase B: conv chunk 0 (stores) || pack xt_lo row 4 (reads)
    bool need_b = false, need_c = false;
    if (isconv) {
        need_b = chunk_hot(0);
    } else {
        int t2 = tid - 448;
        if (t2 < 56) pack_task(xt_lo, 0, 4, t2);
    }
    __syncthreads();

    // ---- phase C: conv chunk 1
    if (isconv) need_c = chunk_hot(1);
    __syncthreads();

    // ---- phase D1 (cold): xt_hi rows 0..5, xt_lo halo rows 0/5, pads, weights
    if (anyneed) {
        if (tid < 336) {
            pack_task(xt_hi, 32, tid / 56, tid % 56);
        } else if (tid < 448) {
            int t2 = tid - 336;
            pack_task(xt_lo, 0, (t2 < 56) ? 0 : 5, t2 % 56);
        } else if (tid < 472) {
            int i  = tid - 448;               // 24 pad-column words
            uint32_t* buf = (i < 12) ? xt_lo : xt_hi;
            int ii = i % 12;
            buf[(ii >> 1) * XT_STRIDE + ((ii & 1) ? 57 : 0)] = 0u;
        }
#pragma unroll
        for (int i = 0; i < 4; ++i) {
            int cw = wid * 4 + i;
            if (needflag[cw]) {               // wave-uniform (same LDS word)
                const float* ws = w + (size_t)cw * (CIN * 9) + (size_t)lane * 9;
#pragma unroll
                for (int k = 0; k < 9; ++k) {
                    uint64_t qb = __ballot(ws[k] > 0.0f);
                    if (lane == 0) wsh[cw * 9 + k] = qb;
                }
            }
        }
    }
    __syncthreads();

    // ---- phase D2 (cold): exact 64-bit 9-tap equality eval for hit chunks
    if (need_b | need_c) {
        uint64_t wpA[9], wpB[9];
#pragma unroll
        for (int k = 0; k < 9; ++k) {
            wpA[k] = wsh[co0 * 9 + k];
            wpB[k] = wsh[(co0 + 1) * 9 + k];
        }
#pragma unroll
        for (int chunk = 0; chunk < 2; ++chunk) {
            bool nd = chunk ? need_c : need_b;
            if (!nd) continue;
            uint64_t rA[4][6];
#pragma unroll
            for (int r = 0; r < 4; ++r)
#pragma unroll
                for (int c = 0; c < 6; ++c) {
                    int idx = (2 * chunk + r) * XT_STRIDE + c0 + c;
                    rA[r][c] = (uint64_t)xt_lo[idx] | ((uint64_t)xt_hi[idx] << 32);
                }
            float* obase = out + ((size_t)n * COUT + co0) * HW
                               + (size_t)(h0 + 2 * chunk) * WWD + c0;
#pragma unroll
            for (int ci = 0; ci < 2; ++ci) {
                int bb = ci ? bb1 : bb0;
                float* ob = obase + (size_t)ci * HW;
#pragma unroll
                for (int r = 0; r < 2; ++r) {
                    float v[4];
#pragma unroll
                    for (int o = 0; o < 4; ++o) {
                        int e = bb;
#pragma unroll
                        for (int kh = 0; kh < 3; ++kh)
#pragma unroll
                            for (int kw = 0; kw < 3; ++kw)
                                e &= (rA[r + kh][o + kw] ==
                                      (ci ? wpB[kh * 3 + kw] : wpA[kh * 3 + kw]));
                        v[o] = e ? 1.0f : 0.0f;
                    }
                    *(float4*)(ob + (size_t)r * WWD) =
                        make_float4(v[0], v[1], v[2], v[3]);
                }
            }
        }
    }
}

extern "C" void kernel_launch(void* const* d_in, const int* in_sizes, int n_in,
                              void* d_out, int out_size, void* d_ws, size_t ws_size,
                              hipStream_t stream) {
    const float* x    = (const float*)d_in[0];
    const float* wgt  = (const float*)d_in[1];
    const float* bias = (const float*)d_in[2];
    float* out = (float*)d_out;

    fused_conv<<<NBLOCKS, NTHREADS, 0, stream>>>(x, wgt, bias, out);
}